// Round 4
// baseline (692.724 us; speedup 1.0000x reference)
//
#include <hip/hip_runtime.h>
#include <hip/hip_bf16.h>

#define BB 256
#define NN 257
#define NT 256   // tokens per batch (N-1)
#define DD 768
#define KC 8     // K clusters
#define VV 10000
#define ITERS 4

#define CHD 32               // sim: dims per staged chunk (128 B / token)
#define NCH (DD / CHD)       // 24 chunks per sim sweep
#define CF4 (CHD / 4)        // 8 float4 per token per chunk
#define CSTR 193             // cent row stride in float4 (772 dwords)

#define ATOK 16              // acc: tokens per streamed chunk
#define ANCH (NT / ATOK)     // 16 chunks per accumulate sweep
#define ACHF (ATOK * DD)     // 12288 floats = 48 KB per acc chunk

__device__ __forceinline__ float waveReduceSum(float v) {
#pragma unroll
    for (int off = 32; off > 0; off >>= 1)
        v += __shfl_xor(v, off, 64);
    return v;
}

__device__ __forceinline__ float dot4chain(float4 a, float4 c, float acc) {
    // exact chain from rounds 1-4 (x,y,z,w ascending)
    return fmaf(a.w, c.w, fmaf(a.z, c.z, fmaf(a.y, c.y, fmaf(a.x, c.x, acc))));
}

// Async global->LDS DMA, 16 B per lane, LDS dest = wave-uniform base + lane*16.
__device__ __forceinline__ void gld16(const float* g, void* lds) {
    __builtin_amdgcn_global_load_lds(
        (const __attribute__((address_space(1))) void*)g,
        (__attribute__((address_space(3))) void*)lds,
        16, 0, 0);
}

// One block (1024 threads, 16 waves) per batch.
//
// R4 change: ACCUMULATE is now producer-consumer DMA-streamed (same T3/T4
// pattern as the sim loop). Waves 12-15 (idle in the old accumulate) are
// producers: global_load_lds the panel token-major in 16-token x 768-dim
// chunks (48 KB) into a double-buffered LDS region, counted vmcnt(12) + raw
// s_barrier (no mid-loop vmcnt(0) drain). Waves 0-11 consume: thread d reads
// v[n,d] by ds_read_b32 (lanes hit consecutive dwords -> 2/bank, conflict
// free) and advances the SAME n-ascending fmaf chains n=0..255 (chunks in
// token order) -> every c1/tsum chain bit-identical to the passing R3 kernel.
// Double barrier per chunk: #1 after producer vmcnt(12) (chunk c visible),
// #2 after consume (chunk c's buffer safe to overwrite with chunk c+2).
//
// LDS: cent 48.25 KB persistent; tbuf region 104 KB shared by phases:
//   sim:  3 x 32 KB triple-buffered dim-chunks   @ [0, 96 KB)
//   acc:  2 x 48 KB double-buffered token-chunks @ [0, 96 KB)
//   maskF [NT][8] floats                         @ [96 KB, 104 KB)
// (maskF written after sim sweep, read through accumulate, dead after.)
// Total 155.9 KB -> still 1 block/CU, 16 waves.
__global__ __launch_bounds__(1024, 4) void kmeans_kernel(
    const float* __restrict__ tokens,
    const float* __restrict__ vc,
    const int* __restrict__ topk,
    float* __restrict__ out_assign,   // (B, 256, 8) float
    float* __restrict__ delta)        // (V) float accumulators (pre-zeroed)
{
    __shared__ float4 cent4[16 * CSTR];       // 49408 B normalized centroids (row = 2k+c)
    __shared__ float4 tbuf4[6656];            // 106496 B shared staging region
    __shared__ int sidx[KC];

    float* centf = (float*)cent4;
    float* tfl   = (float*)tbuf4;
    float (*maskF)[KC] = (float (*)[KC])((char*)tbuf4 + 98304);   // [NT][8] @ +96 KB

    const int b = blockIdx.x;
    const int t = threadIdx.x;
    const int lane = t & 63;
    const int wave = t >> 6;

    if (t < KC) sidx[t] = topk[b * KC + t];
    __syncthreads();

    // ---- gather + L2-normalize 16 initial centroid rows: wave r -> row r
    {
        const int r = wave;
        const int k = r >> 1, c = r & 1;
        const float* src = vc + ((size_t)sidx[k] * 2 + c) * DD;
        float vals[12];
        float ss = 0.f;
#pragma unroll
        for (int j = 0; j < 12; ++j) {
            vals[j] = src[lane + 64 * j];
            ss = fmaf(vals[j], vals[j], ss);
        }
        ss = waveReduceSum(ss);
        float iv = 1.0f / fmaxf(sqrtf(ss), 1e-12f);
#pragma unroll
        for (int j = 0; j < 12; ++j)
            centf[r * 772 + lane + 64 * j] = vals[j] * iv;
    }
    __syncthreads();

    const float* tpb = tokens + ((size_t)b * NN + 1) * DD;

    // sim roles: thread = (token, row-group of 4)
    const int tok = t & 255;
    const int g   = t >> 8;
    const int s7  = tok & 7;

    // sim DMA lane roles: wave handles chunk slots [wave*128, wave*128+128)
    const int slotA = wave * 128 + lane;         // load 0
    const int slotB = slotA + 64;                // load 1
    const float* gbaseA = tpb + (size_t)(slotA >> 3) * DD + 4 * ((slotA & 7) ^ ((slotA >> 3) & 7));
    const float* gbaseB = tpb + (size_t)(slotB >> 3) * DD + 4 * ((slotB & 7) ^ ((slotB >> 3) & 7));

    // acc producer roles: wave p=wave-12 owns 12 x 1KB segments per chunk
    const int p = wave - 12;                      // valid when wave>=12
    const float* asrc = tpb + (size_t)(p >= 0 ? p : 0) * 12 * 256 + lane * 4;
    float* adst = tfl + (p >= 0 ? p : 0) * 12 * 256;

    float tsum_reg = 0.f;   // per-dim token sum, computed it=0, reused it=1..3

    for (int it = 0; it < ITERS; ++it) {
        float acc[4] = {0.f, 0.f, 0.f, 0.f};

        // ======================== SIM SWEEP (unchanged R3) ========================
        gld16(gbaseA,       (void*)(tbuf4 + wave * 128));
        gld16(gbaseB,       (void*)(tbuf4 + wave * 128 + 64));
        gld16(gbaseA + CHD, (void*)(tbuf4 + 2048 + wave * 128));
        gld16(gbaseB + CHD, (void*)(tbuf4 + 2048 + wave * 128 + 64));

#pragma unroll 1
        for (int cix = 0; cix < NCH - 1; ++cix) {
            asm volatile("s_waitcnt vmcnt(2)" ::: "memory");
            __builtin_amdgcn_s_barrier();
            __builtin_amdgcn_sched_barrier(0);
            if (cix + 2 < NCH) {
                const int nb = (cix + 2) % 3;
                gld16(gbaseA + (cix + 2) * CHD, (void*)(tbuf4 + nb * 2048 + wave * 128));
                gld16(gbaseB + (cix + 2) * CHD, (void*)(tbuf4 + nb * 2048 + wave * 128 + 64));
            }
            {
                const float4* tb = tbuf4 + (cix % 3) * 2048 + (tok << 3);
                const float4* cr = cent4 + (g * 4) * CSTR + (cix << 3);
#pragma unroll
                for (int j4 = 0; j4 < CF4; ++j4) {
                    float4 a  = tb[j4 ^ s7];
                    float4 c0 = cr[j4];
                    float4 c1 = cr[CSTR + j4];
                    float4 c2 = cr[2 * CSTR + j4];
                    float4 c3 = cr[3 * CSTR + j4];
                    acc[0] = dot4chain(a, c0, acc[0]);
                    acc[1] = dot4chain(a, c1, acc[1]);
                    acc[2] = dot4chain(a, c2, acc[2]);
                    acc[3] = dot4chain(a, c3, acc[3]);
                }
            }
        }
        __syncthreads();   // tail drain (chunk 23)
        {
            const int cix = NCH - 1;
            const float4* tb = tbuf4 + (cix % 3) * 2048 + (tok << 3);
            const float4* cr = cent4 + (g * 4) * CSTR + (cix << 3);
#pragma unroll
            for (int j4 = 0; j4 < CF4; ++j4) {
                float4 a  = tb[j4 ^ s7];
                float4 c0 = cr[j4];
                float4 c1 = cr[CSTR + j4];
                float4 c2 = cr[2 * CSTR + j4];
                float4 c3 = cr[3 * CSTR + j4];
                acc[0] = dot4chain(a, c0, acc[0]);
                acc[1] = dot4chain(a, c1, acc[1]);
                acc[2] = dot4chain(a, c2, acc[2]);
                acc[3] = dot4chain(a, c3, acc[3]);
            }
        }

        // ---- masks: thread (g,tok) writes float {0,1} for clusters (2g, 2g+1)
        {
            float2 mf;
            mf.x = (acc[1] > acc[0]) ? 1.f : 0.f;    // cluster 2g   (ties -> 0)
            mf.y = (acc[3] > acc[2]) ? 1.f : 0.f;    // cluster 2g+1
            *(float2*)&maskF[tok][2 * g] = mf;
        }
        __syncthreads();   // masks visible; sim buffers all consumed -> acc may stage

        if (it == ITERS - 1 && t < NT) {
            const float4* mf4 = (const float4*)&maskF[t][0];
            float4* op = (float4*)(out_assign + ((size_t)b * NT + t) * KC);
            op[0] = mf4[0]; op[1] = mf4[1];
        }

        // ==================== ACCUMULATE: producer-consumer ====================
        // prologue: producers issue chunks 0 and 1
        if (wave >= 12) {
#pragma unroll
            for (int j = 0; j < 12; ++j)
                gld16(asrc + j * 256, (void*)(adst + j * 256));
#pragma unroll
            for (int j = 0; j < 12; ++j)
                gld16(asrc + ACHF + j * 256, (void*)(adst + ACHF + j * 256));
        }

        float a0 = 0.f, a1 = 0.f, a2 = 0.f, a3 = 0.f;
        float a4 = 0.f, a5 = 0.f, a6 = 0.f, a7 = 0.f;
        float tr = 0.f;

#pragma unroll 1
        for (int c = 0; c < ANCH; ++c) {
            if (wave >= 12) {
                if (c < ANCH - 1) asm volatile("s_waitcnt vmcnt(12)" ::: "memory");
                else              asm volatile("s_waitcnt vmcnt(0)"  ::: "memory");
            }
            __builtin_amdgcn_s_barrier();            // #1: chunk c visible to all
            __builtin_amdgcn_sched_barrier(0);
            if (t < DD) {
                const float* cb = tfl + (c & 1) * ACHF + t;
#pragma unroll
                for (int i = 0; i < ATOK; ++i) {
                    float v = cb[i * DD];                          // conflict-free b32
                    const float4* mr = (const float4*)&maskF[c * ATOK + i][0];
                    float4 ma = mr[0];                             // uniform broadcasts
                    float4 mb = mr[1];
                    a0 = fmaf(v, ma.x, a0);
                    a1 = fmaf(v, ma.y, a1);
                    a2 = fmaf(v, ma.z, a2);
                    a3 = fmaf(v, ma.w, a3);
                    a4 = fmaf(v, mb.x, a4);
                    a5 = fmaf(v, mb.y, a5);
                    a6 = fmaf(v, mb.z, a6);
                    a7 = fmaf(v, mb.w, a7);
                    if (it == 0) tr += v;                          // n-ascending chain
                }
            }
            __builtin_amdgcn_s_barrier();            // #2: chunk c consumed by all
            __builtin_amdgcn_sched_barrier(0);
            if (wave >= 12 && c + 2 < ANCH) {
                // refill chunk c's buffer (consumed at barrier #2) with chunk c+2
#pragma unroll
                for (int j = 0; j < 12; ++j)
                    gld16(asrc + (size_t)(c + 2) * ACHF + j * 256,
                          (void*)(adst + (c & 1) * ACHF + j * 256));
            }
        }

        if (t < DD) {
            const int d = t;
            if (it == 0) tsum_reg = tr;
            // rows r=2k+1 get a_k; rows r=2k get tsum-a_k (same subtraction as
            // the old normalize path -> identical values)
            centf[ 1 * 772 + d] = a0;  centf[ 0 * 772 + d] = tsum_reg - a0;
            centf[ 3 * 772 + d] = a1;  centf[ 2 * 772 + d] = tsum_reg - a1;
            centf[ 5 * 772 + d] = a2;  centf[ 4 * 772 + d] = tsum_reg - a2;
            centf[ 7 * 772 + d] = a3;  centf[ 6 * 772 + d] = tsum_reg - a3;
            centf[ 9 * 772 + d] = a4;  centf[ 8 * 772 + d] = tsum_reg - a4;
            centf[11 * 772 + d] = a5;  centf[10 * 772 + d] = tsum_reg - a5;
            centf[13 * 772 + d] = a6;  centf[12 * 772 + d] = tsum_reg - a6;
            centf[15 * 772 + d] = a7;  centf[14 * 772 + d] = tsum_reg - a7;
        }
        __syncthreads();

        // ==== normalize in place: wave r reads its centf row, reduces, scales
        {
            const int r = wave;
            float vals[12];
            float ss = 0.f;
#pragma unroll
            for (int j = 0; j < 12; ++j) {
                vals[j] = centf[r * 772 + lane + 64 * j];
                ss = fmaf(vals[j], vals[j], ss);
            }
            ss = waveReduceSum(ss);
            float iv = 1.0f / fmaxf(sqrtf(ss), 1e-12f);
#pragma unroll
            for (int j = 0; j < 12; ++j)
                centf[r * 772 + lane + 64 * j] = vals[j] * iv;
        }
        __syncthreads();   // cent ready; tbuf region free for next iter's staging
    }

    // ---- scatter: vc[idx,0,0] += centroids_final[b,k,0,0] (c0 row, element 0)
    if (t < KC) {
        atomicAdd(delta + sidx[t], centf[(2 * t) * 772]);
    }
}

__global__ __launch_bounds__(1024) void vcnorm_kernel(
    const float* __restrict__ vc,
    const float* __restrict__ delta,
    float* __restrict__ out)          // (V, 2, D)
{
    const int t = threadIdx.x;
    const int lane = t & 63;
    const int wave = t >> 6;
    const int r = blockIdx.x * 16 + wave;     // row in [0, 2V)
    if (r >= 2 * VV) return;
    const int v = r >> 1;
    const int c = r & 1;
    const float* src = vc + (size_t)r * DD;
    float4 x[3];
#pragma unroll
    for (int j = 0; j < 3; ++j)
        x[j] = *(const float4*)(src + (lane + 64 * j) * 4);
    if (c == 0 && lane == 0) x[0].x += delta[v];
    float ss = 0.f;
#pragma unroll
    for (int j = 0; j < 3; ++j)
        ss += x[j].x * x[j].x + x[j].y * x[j].y + x[j].z * x[j].z + x[j].w * x[j].w;
    ss = waveReduceSum(ss);
    float iv = 1.0f / fmaxf(sqrtf(ss), 1e-12f);
    float* dst = out + (size_t)r * DD;
#pragma unroll
    for (int j = 0; j < 3; ++j) {
        float4 y = make_float4(x[j].x * iv, x[j].y * iv, x[j].z * iv, x[j].w * iv);
        *(float4*)(dst + (lane + 64 * j) * 4) = y;
    }
}

extern "C" void kernel_launch(void* const* d_in, const int* in_sizes, int n_in,
                              void* d_out, int out_size, void* d_ws, size_t ws_size,
                              hipStream_t stream) {
    const float* tokens = (const float*)d_in[0];
    const float* vc     = (const float*)d_in[1];
    const int*   topk   = (const int*)d_in[2];
    float* out          = (float*)d_out;
    float* assignments  = out;                                   // B*NT*KC floats
    float* vcnew        = out + (size_t)BB * NT * KC;            // V*2*D floats
    float* delta        = (float*)d_ws;                          // V floats

    hipMemsetAsync(delta, 0, VV * sizeof(float), stream);
    hipLaunchKernelGGL(kmeans_kernel, dim3(BB), dim3(1024), 0, stream,
                       tokens, vc, topk, assignments, delta);
    hipLaunchKernelGGL(vcnorm_kernel, dim3((2 * VV + 15) / 16), dim3(1024), 0, stream,
                       vc, delta, vcnew);
}